// Round 4
// baseline (3346.333 us; speedup 1.0000x reference)
//
#include <hip/hip_runtime.h>
#include <hip/hip_bf16.h>

using bf16 = __hip_bfloat16;
typedef __attribute__((ext_vector_type(8))) short bfrag;   // 8 bf16 (4 VGPRs)
typedef __attribute__((ext_vector_type(4))) float ffrag;   // 4 fp32 acc

constexpr int kH  = 32;    // hidden
constexpr int kE  = 64;    // embed
constexpr int kV  = 258;   // vocab
constexpr int kB  = 16;    // batch
constexpr int kR  = 64;    // rows
constexpr int kS  = 64;    // cols
constexpr int kG  = 96;    // 3*H
constexpr int kEP = 65;    // E+1

// ---------------- workspace layout (unchanged) ----------------
constexpr int H2_OFF   = (3*kB*kR*kS*kH)/2;
constexpr int PROG_OFF = H2_OFF;                      // legacy progress flags (unused now)
constexpr int T_OFF    = H2_OFF + kB*kR*kH;           // [3][258][96]  emb@Wih0[:, :64].T (+bias fold)
constexpr int WPH_OFF  = T_OFF + 3*kV*kG;             // [3][96][32]   Wih0 @ h2e_W  fold
constexpr int WADP_OFF = WPH_OFF + 3*kG*kH;           // [2][96][32]   Wih0 @ adp_W  fold
constexpr int C0_OFF   = WADP_OFF + 2*kG*kH;          // [3][96]
constexpr int RW_OFF   = C0_OFF + 3*kG;               // [3][96]
constexpr int TG_OFF   = RW_OFF + 3*kG;               // [258][258]
constexpr int TBR_OFF  = TG_OFF + kV*kV;              // [258][258]
constexpr int TBG_OFF  = TBR_OFF + kV*kV;             // [258][258]
constexpr int P_EMB    = TBG_OFF + kV*kV;
constexpr int P_WIH0   = P_EMB    + 3*kV*kE;
constexpr int P_WIHR   = P_WIH0   + 3*kG*kEP;
constexpr int P_WHH    = P_WIHR   + 3*2*kG*kH;
constexpr int P_BIH    = P_WHH    + 3*3*kG*kH;
constexpr int P_BHH    = P_BIH    + 3*3*kG;
constexpr int P_H2EW   = P_BHH    + 3*3*kG;
constexpr int P_H2EB   = P_H2EW   + 3*kEP*kH;
constexpr int P_ADPW   = P_H2EB   + 3*kEP;
constexpr int P_ADPB   = P_ADPW   + 2*kEP*kH;
constexpr int P_REDW   = P_ADPB   + 2*kEP;
constexpr int P_REDB   = P_REDW   + kV*kH;
constexpr int P_GREENW = P_REDB   + kV;
constexpr int P_GREENB = P_GREENW + kV*(kH+kE);
constexpr int P_BLUEW  = P_GREENB + kV;
constexpr int P_BLUEB  = P_BLUEW  + kV*(kH+2*kE);
constexpr int WS_END   = P_BLUEB  + kV;               // ~14.0 MB

__device__ __forceinline__ float tof(bf16 h) { return __bfloat162float(h); }

__device__ __forceinline__ unsigned short bfbits(bf16 h) {
  union { bf16 h; unsigned short u; } cv; cv.h = h; return cv.u;
}
__device__ __forceinline__ short f2b(float v) {
  return (short)bfbits(__float2bfloat16(v));
}
__device__ __forceinline__ float sigm(float v) { return 1.0f / (1.0f + __expf(-v)); }
__device__ __forceinline__ float tanh_(float v) { return 1.0f - 2.0f / (__expf(2.0f * v) + 1.0f); }

#define MFMA16(a, bb, cc) __builtin_amdgcn_mfma_f32_16x16x32_bf16((a), (bb), (cc), 0, 0, 0)

// LDS-only barrier: raw s_barrier with lgkmcnt(0) only. Global loads/stores
// (outs writes, T-table prefetch) stay in flight ACROSS the barrier -- the
// __syncthreads vmcnt(0) drain was ~500-1000 serial cycles per step and
// serves no intra-kernel purpose (outs is only read by the next kernel).
__device__ __forceinline__ void lds_barrier() {
  __builtin_amdgcn_sched_barrier(0);
  asm volatile("s_waitcnt lgkmcnt(0)" ::: "memory");
  __builtin_amdgcn_s_barrier();
  __builtin_amdgcn_sched_barrier(0);
}

// ---------------- dtype detect + normalize to fp32 (unchanged, verified) ----------------
__global__ void norm_kernel(const void* p0, const void* p1, const void* p2, const void* p3,
                            const void* p4, const void* p5, const void* p6, const void* p7,
                            const void* p8, const void* p9, const void* p10, const void* p11,
                            const void* p12, const void* p13, const void* p14, const void* p15,
                            float* __restrict__ wsf)
{
  constexpr int counts[16] = {3*kV*kE, 3*kG*kEP, 3*2*kG*kH, 3*3*kG*kH, 3*3*kG, 3*3*kG,
                              3*kEP*kH, 3*kEP, 2*kEP*kH, 2*kEP, kV*kH, kV,
                              kV*(kH+kE), kV, kV*(kH+2*kE), kV};
  constexpr int dsts[16] = {P_EMB, P_WIH0, P_WIHR, P_WHH, P_BIH, P_BHH,
                            P_H2EW, P_H2EB, P_ADPW, P_ADPB, P_REDW, P_REDB,
                            P_GREENW, P_GREENB, P_BLUEW, P_BLUEB};
  const void* srcs[16] = {p0,p1,p2,p3,p4,p5,p6,p7,p8,p9,p10,p11,p12,p13,p14,p15};

  __shared__ unsigned int smax;
  const int a = blockIdx.x;
  const void* src = srcs[a];
  const int n = counts[a];
  if (threadIdx.x == 0) smax = 0;
  if (a == 0) {
    int* prog = (int*)(wsf + PROG_OFF);
    for (int i = threadIdx.x; i < 48; i += 256) prog[i] = 0;
  }
  __syncthreads();

  const unsigned short* u16 = (const unsigned short*)src;
  const int ns = (n < 2048) ? n : 2048;
  unsigned int lm = 0;
  for (int i = threadIdx.x; i < ns; i += 256) {
    unsigned int e = ((unsigned int)u16[i] >> 7) & 0xFFu;
    if (e > lm) lm = e;
  }
  atomicMax(&smax, lm);
  __syncthreads();

  const bool isf32 = (smax >= 135);
  float* dst = wsf + dsts[a];
  if (isf32) {
    const float* s = (const float*)src;
    for (int i = threadIdx.x; i < n; i += 256) dst[i] = s[i];
  } else {
    const bf16* s = (const bf16*)src;
    for (int i = threadIdx.x; i < n; i += 256) dst[i] = tof(s[i]);
  }
}

// ---------------- prep: fold tables & matrices (unchanged, verified) ----------------
__global__ void prep_kernel(float* __restrict__ wsf)
{
  int idx = blockIdx.x * 256 + threadIdx.x;

  if (idx < 3*kV*kG) {
    int c = idx / (kV*kG);
    int rem = idx - c*(kV*kG);
    int v = rem / kG;
    int j = rem - v*kG;
    const float* ev = wsf + P_EMB + (c*kV + v)*kE;
    const float* wr = wsf + P_WIH0 + (c*kG + j)*kEP;
    float acc = 0.f;
    for (int e = 0; e < kE; ++e) acc = fmaf(ev[e], wr[e], acc);
    wsf[T_OFF + idx] = acc;
    return;
  }
  idx -= 3*kV*kG;

  if (idx < 3*kG*kH) {
    int c = idx / (kG*kH);
    int rem = idx - c*(kG*kH);
    int j = rem >> 5;
    int k = rem & 31;
    const float* wr = wsf + P_WIH0 + (c*kG + j)*kEP;
    const float* hw = wsf + P_H2EW + c*kEP*kH + k;
    float acc = 0.f;
    for (int e = 0; e < kEP; ++e) acc = fmaf(wr[e], hw[e*kH], acc);
    wsf[WPH_OFF + idx] = acc;
    return;
  }
  idx -= 3*kG*kH;

  if (idx < 2*kG*kH) {
    int cm = idx / (kG*kH);
    int rem = idx - cm*(kG*kH);
    int j = rem >> 5;
    int k = rem & 31;
    const float* wr = wsf + P_WIH0 + ((cm+1)*kG + j)*kEP;
    const float* aw = wsf + P_ADPW + cm*kEP*kH + k;
    float acc = 0.f;
    for (int e = 0; e < kEP; ++e) acc = fmaf(wr[e], aw[e*kH], acc);
    wsf[WADP_OFF + idx] = acc;
    return;
  }
  idx -= 2*kG*kH;

  if (idx < 3*kG) {
    int c = idx / kG;
    int j = idx - c*kG;
    const float* wr = wsf + P_WIH0 + (c*kG + j)*kEP;
    float acc = wsf[P_BIH + (c*3 + 0)*kG + j];
    for (int e = 0; e < kEP; ++e) acc = fmaf(wsf[P_H2EB + c*kEP + e], wr[e], acc);
    if (c > 0)
      for (int e = 0; e < kEP; ++e) acc = fmaf(wsf[P_ADPB + (c-1)*kEP + e], wr[e], acc);
    wsf[C0_OFF + idx] = acc;
    return;
  }
  idx -= 3*kG;

  if (idx < 3*kG) {
    int c = idx / kG;
    int j = idx - c*kG;
    wsf[RW_OFF + idx] = wsf[P_WIH0 + (c*kG + j)*kEP + kE];
    return;
  }
  idx -= 3*kG;

  if (idx < kV*kV) {
    int v = idx / kV, w = idx - (idx / kV)*kV;
    const float* ev = wsf + P_EMB + v*kE;
    const float* gw = wsf + P_GREENW + w*(kH + kE) + kH;
    float acc = 0.f;
    for (int e = 0; e < kE; ++e) acc = fmaf(ev[e], gw[e], acc);
    wsf[TG_OFF + idx] = acc;
    return;
  }
  idx -= kV*kV;

  if (idx < kV*kV) {
    int v = idx / kV, w = idx - (idx / kV)*kV;
    const float* ev = wsf + P_EMB + v*kE;
    const float* bw = wsf + P_BLUEW + w*(kH + 2*kE) + kH;
    float acc = 0.f;
    for (int e = 0; e < kE; ++e) acc = fmaf(ev[e], bw[e], acc);
    wsf[TBR_OFF + idx] = acc;
    return;
  }
  idx -= kV*kV;

  if (idx < kV*kV) {
    int v = idx / kV, w = idx - (idx / kV)*kV;
    const float* ev = wsf + P_EMB + (kV + v)*kE;
    const float* bw = wsf + P_BLUEW + w*(kH + 2*kE) + kH + kE;
    float acc = 0.f;
    for (int e = 0; e < kE; ++e) acc = fmaf(ev[e], bw[e], acc);
    wsf[TBG_OFF + idx] = acc;
  }
}

// ---------------- fold layer-0 gate constants into T ----------------
// T[c][v][g] += C0[c][g] + (g < 64 ? BHH0[c][g] : 0)
__global__ void tfold_kernel(float* __restrict__ wsf)
{
  int idx = blockIdx.x * 256 + threadIdx.x;
  if (idx >= 3*kV*kG) return;
  int c = idx / (kV*kG);
  int g = idx % kG;
  float add = wsf[C0_OFF + c*kG + g];
  if (g < 2*kH) add += wsf[P_BHH + (c*3 + 0)*kG + g];
  wsf[T_OFF + idx] += add;
}

// ---------------- fused 3-channel wavefront recurrence: 12 waves / block ----------------
// Grid = 16 blocks (one per batch). Block = 768 = 12 waves: wave = c*4 + w.
// Round-3 lesson: step time = per-wave serial CHAIN latency (barrier locks all
// waves to one step; occupancy fills nothing). This round attacks the chain:
//  (1) raw s_barrier + lgkmcnt-only (no vmcnt(0) drain of outs-stores/T-loads),
//  (2) T-table gather software-pipelined one diagonal ahead + T-add moved
//      AFTER the layer-0 MFMAs (zero-init accumulators; same math mod fp32
//      add order; inactive cells were already garbage-and-discarded),
//  (3) layer-1/2 + Whh0 weights back in VGPRs (round-1 proved 120 regs fit);
//      only Wph/Wadp stream from LDS, frag-major (lane*16B, conflict-free).
__global__ __launch_bounds__(768, 3)
void recur_all_kernel(const int* __restrict__ x, float* __restrict__ wsf)
{
  __shared__ __align__(16) short lds[12288 + 12288 + 5*6*64*8];   // 78.7 KB
  short* RING = lds;            // [3][2][64][32] layer-2 outputs, slot = diag&1
  short* H01  = lds + 12288;    // [3][2(layer)][64][32]
  short* WLf  = lds + 24576;    // [5 mats][6 u][64 lane][8] frag-major bf16

  const int tid  = threadIdx.x;
  const int b    = blockIdx.x;
  const int wave = tid >> 6;
  const int c    = wave >> 2;        // channel
  const int w    = wave & 3;         // 16-row band
  const int lane = tid & 63;
  const int m    = lane & 15;
  const int q    = lane >> 4;
  const int ln   = m;
  const int cb0  = w * 16;

  for (int i = tid; i < 24576; i += 768) lds[i] = 0;

  // ---- stage Wph(3) + Wadp(2) into LDS, frag-major: [(mat*6+u)*64 + lane]*8 + j ----
  for (int idx = tid; idx < 5*6*64*8; idx += 768) {
    int j     = idx & 7;
    int lanei = (idx >> 3) & 63;
    int u     = (idx >> 9) % 6;
    int mat   = idx / (6*64*8);
    const int off = (mat < 3) ? WPH_OFF + mat*kG*kH : WADP_OFF + (mat-3)*kG*kH;
    WLf[idx] = f2b(wsf[off + (u*16 + (lanei & 15))*kH + (lanei >> 4)*8 + j]);
  }

  // ---- register weights: Whh0, Wih1, Whh1, Wih2, Whh2 (120 VGPRs) ----
  const float* wsrc[5];
  wsrc[0] = wsf + P_WHH  + (c*3+0)*kG*kH;
  wsrc[1] = wsf + P_WIHR + (c*2+0)*kG*kH;
  wsrc[2] = wsf + P_WHH  + (c*3+1)*kG*kH;
  wsrc[3] = wsf + P_WIHR + (c*2+1)*kG*kH;
  wsrc[4] = wsf + P_WHH  + (c*3+2)*kG*kH;
  bfrag Wr[5][6];
#pragma unroll
  for (int mt = 0; mt < 5; ++mt) {
#pragma unroll
    for (int u = 0; u < 6; ++u) {
      const float* p = wsrc[mt] + (u*16 + ln)*kH + q*8;
#pragma unroll
      for (int j = 0; j < 8; ++j) Wr[mt][u][j] = f2b(p[j]);
    }
  }

  // ---- per-lane gate constants (layer-0 c0/bias terms folded into T) ----
  float rwt[6], bh0n[2], bi1z[4], bi1n[2], bh1n[2], bi2z[4], bi2n[2], bh2n[2];
#pragma unroll
  for (int u = 0; u < 6; ++u) rwt[u] = wsf[RW_OFF + c*kG + u*16 + ln];
#pragma unroll
  for (int u = 0; u < 4; ++u) {
    int g = u*16 + ln;
    bi1z[u] = wsf[P_BIH + (c*3+1)*kG + g] + wsf[P_BHH + (c*3+1)*kG + g];
    bi2z[u] = wsf[P_BIH + (c*3+2)*kG + g] + wsf[P_BHH + (c*3+2)*kG + g];
  }
#pragma unroll
  for (int t2 = 0; t2 < 2; ++t2) {
    int g = 64 + t2*16 + ln;
    bh0n[t2] = wsf[P_BHH + (c*3+0)*kG + g];
    bi1n[t2] = wsf[P_BIH + (c*3+1)*kG + g];
    bh1n[t2] = wsf[P_BHH + (c*3+1)*kG + g];
    bi2n[t2] = wsf[P_BIH + (c*3+2)*kG + g];
    bh2n[t2] = wsf[P_BHH + (c*3+2)*kG + g];
  }

  float h0s[8], h1s[8], h2s[8];
#pragma unroll
  for (int i = 0; i < 8; ++i) { h0s[i] = 0.f; h1s[i] = 0.f; h2s[i] = 0.f; }

  const short* wphL = WLf + c*3072 + lane*8;                   // + u*512
  const short* wadL = WLf + (3 + (c>0?c-1:0))*3072 + lane*8;
#define BFR(base, u) (*(const bfrag*)((base) + (u)*512))

  short* ringc = RING + c*2*2048;                       // [2][64][32]
  const short* ringp = RING + (c>0 ? c-1 : 0)*2*2048;
  short* h0pl = H01 + (c*2 + 0)*2048;
  short* h1pl = H01 + (c*2 + 1)*2048;

  unsigned short* outsC = (unsigned short*)wsf + (size_t)(c*kB + b) * (kR*kS*kH);
  const int* xc = x + (b*3 + c) * kR * kS;
  const float* Tc = wsf + T_OFF + (size_t)c * kV * kG;

  // ---- per-wave constants for the T pipeline ----
  int rr0[4]; float rpw[4];
  bool act_ok; // unused placeholder to keep structure clear
  (void)act_ok;
#pragma unroll
  for (int i = 0; i < 4; ++i) {
    rr0[i] = cb0 + q*4 + i;
    rpw[i] = (float)rr0[i] * (2.0f/64.0f) - 1.0f;
  }

  // T-value software pipeline: tv holds the gather for the NEXT diagonal this
  // wave will process. Loads issued ~a full step before consumption.
  float tv[6][4];
  auto load_tv = [&](int dd) {
#pragma unroll
    for (int i = 0; i < 4; ++i) {
      int sv = dd - rr0[i];
      int scl = sv < 0 ? 0 : (sv > 63 ? 63 : sv);
      int xiv = xc[rr0[i]*kS + scl];
      const float* tp = Tc + (size_t)xiv*kG;
#pragma unroll
      for (int u = 0; u < 6; ++u) tv[u][i] = tp[u*16 + ln];
    }
  };
  load_tv(cb0);   // prefetch for this wave's first active diagonal

  __syncthreads();

  constexpr int TT = kR + kS - 1 + 2;   // 129
  for (int t = 0; t < TT; ++t) {
    const int d = t - c;
    if (d >= cb0 && d <= cb0 + 78) {
      const int ps = (d - 1) & 1;
      const int cs = d & 1;

      int ssv[4];
      bool act[4];
#pragma unroll
      for (int i = 0; i < 4; ++i) {
        ssv[i] = d - rr0[i];
        act[i] = ((unsigned)ssv[i]) < 64u;
      }
      const int row = cb0 + m;

      bfrag phA, h0A, poA;
      {
        int pr = row - 1;
        int prc = pr < 0 ? 0 : pr;
        phA = *(const bfrag*)&RING[(c*2 + ps)*2048 + prc*32 + q*8];
        if (pr < 0) {
#pragma unroll
          for (int j = 0; j < 8; ++j) phA[j] = 0;
        }
        h0A = *(const bfrag*)&h0pl[row*32 + q*8];
        if (c > 0)
          poA = *(const bfrag*)&ringp[cs*2048 + row*32 + q*8];
      }

      // ---- layer 0: zero-init, MFMA chain first, T-add after ----
      ffrag rz[4], gn[2], hn[2];
#pragma unroll
      for (int u = 0; u < 4; ++u)
#pragma unroll
        for (int i = 0; i < 4; ++i) rz[u][i] = 0.f;
#pragma unroll
      for (int t2 = 0; t2 < 2; ++t2)
#pragma unroll
        for (int i = 0; i < 4; ++i) { gn[t2][i] = 0.f; hn[t2][i] = bh0n[t2]; }

#pragma unroll
      for (int u = 0; u < 4; ++u)
        rz[u] = MFMA16(phA, BFR(wphL, u), rz[u]);
#pragma unroll
      for (int t2 = 0; t2 < 2; ++t2)
        gn[t2] = MFMA16(phA, BFR(wphL, 4+t2), gn[t2]);
      if (c > 0) {
#pragma unroll
        for (int u = 0; u < 4; ++u)
          rz[u] = MFMA16(poA, BFR(wadL, u), rz[u]);
#pragma unroll
        for (int t2 = 0; t2 < 2; ++t2)
          gn[t2] = MFMA16(poA, BFR(wadL, 4+t2), gn[t2]);
      }
#pragma unroll
      for (int u = 0; u < 4; ++u)
        rz[u] = MFMA16(h0A, Wr[0][u], rz[u]);
#pragma unroll
      for (int t2 = 0; t2 < 2; ++t2)
        hn[t2] = MFMA16(h0A, Wr[0][4+t2], hn[t2]);

      // consume prefetched T values (garbage for inactive cells -> discarded)
#pragma unroll
      for (int u = 0; u < 4; ++u)
#pragma unroll
        for (int i = 0; i < 4; ++i) rz[u][i] += tv[u][i] + rpw[i]*rwt[u];
#pragma unroll
      for (int t2 = 0; t2 < 2; ++t2)
#pragma unroll
        for (int i = 0; i < 4; ++i) gn[t2][i] += tv[4+t2][i] + rpw[i]*rwt[4+t2];

      // prefetch next diagonal's T gather (before this step's global stores,
      // so the next consume's vmcnt wait does not imply store drain)
      if (d < cb0 + 78) load_tv(d + 1);

#pragma unroll
      for (int i = 0; i < 4; ++i)
#pragma unroll
        for (int th = 0; th < 2; ++th) {
          float rg = sigm(rz[th][i]);
          float zg = sigm(rz[2+th][i]);
          float ng = tanh_(gn[th][i] + rg*hn[th][i]);
          float h0v = (1.f - zg)*ng + zg*h0s[i*2+th];
          if (act[i]) {
            h0s[i*2+th] = h0v;
            h0pl[rr0[i]*32 + th*16 + ln] = f2b(h0v);
          }
        }
      bfrag h0An = *(const bfrag*)&h0pl[row*32 + q*8];

      // ---- layer 1 ----
      bfrag h1A = *(const bfrag*)&h1pl[row*32 + q*8];
      ffrag rz1[4], gn1[2], hn1[2];
#pragma unroll
      for (int u = 0; u < 4; ++u)
#pragma unroll
        for (int i = 0; i < 4; ++i) rz1[u][i] = bi1z[u];
#pragma unroll
      for (int t2 = 0; t2 < 2; ++t2)
#pragma unroll
        for (int i = 0; i < 4; ++i) { gn1[t2][i] = bi1n[t2]; hn1[t2][i] = bh1n[t2]; }
#pragma unroll
      for (int u = 0; u < 4; ++u) {
        rz1[u] = MFMA16(h0An, Wr[1][u], rz1[u]);
        rz1[u] = MFMA16(h1A,  Wr[2][u], rz1[u]);
      }
#pragma unroll
      for (int t2 = 0; t2 < 2; ++t2) {
        gn1[t2] = MFMA16(h0An, Wr[1][4+t2], gn1[t2]);
        hn1[t2] = MFMA16(h1A,  Wr[2][4+t2], hn1[t2]);
      }
#pragma unroll
      for (int i = 0; i < 4; ++i)
#pragma unroll
        for (int th = 0; th < 2; ++th) {
          float rg = sigm(rz1[th][i]);
          float zg = sigm(rz1[2+th][i]);
          float ng = tanh_(gn1[th][i] + rg*hn1[th][i]);
          float h1v = (1.f - zg)*ng + zg*h1s[i*2+th];
          if (act[i]) {
            h1s[i*2+th] = h1v;
            h1pl[rr0[i]*32 + th*16 + ln] = f2b(h1v);
          }
        }
      bfrag h1An = *(const bfrag*)&h1pl[row*32 + q*8];

      // ---- layer 2 ----
      bfrag h2A = *(const bfrag*)&ringc[ps*2048 + row*32 + q*8];
      if (m == d - cb0) {            // this A-row's cell has s==0 -> no left neighbor
#pragma unroll
        for (int j = 0; j < 8; ++j) h2A[j] = 0;
      }
      ffrag rz2[4], gn2[2], hn2[2];
#pragma unroll
      for (int u = 0; u < 4; ++u)
#pragma unroll
        for (int i = 0; i < 4; ++i) rz2[u][i] = bi2z[u];
#pragma unroll
      for (int t2 = 0; t2 < 2; ++t2)
#pragma unroll
        for (int i = 0; i < 4; ++i) { gn2[t2][i] = bi2n[t2]; hn2[t2][i] = bh2n[t2]; }
#pragma unroll
      for (int u = 0; u < 4; ++u) {
        rz2[u] = MFMA16(h1An, Wr[3][u], rz2[u]);
        rz2[u] = MFMA16(h2A,  Wr[4][u], rz2[u]);
      }
#pragma unroll
      for (int t2 = 0; t2 < 2; ++t2) {
        gn2[t2] = MFMA16(h1An, Wr[3][4+t2], gn2[t2]);
        hn2[t2] = MFMA16(h2A,  Wr[4][4+t2], hn2[t2]);
      }
#pragma unroll
      for (int i = 0; i < 4; ++i)
#pragma unroll
        for (int th = 0; th < 2; ++th) {
          float rg = sigm(rz2[th][i]);
          float zg = sigm(rz2[2+th][i]);
          float ng = tanh_(gn2[th][i] + rg*hn2[th][i]);
          float h2old = (ssv[i] == 0) ? 0.f : h2s[i*2+th];
          float h2v = (1.f - zg)*ng + zg*h2old;
          if (act[i]) {
            h2s[i*2+th] = h2v;
            short hb = f2b(h2v);
            ringc[cs*2048 + rr0[i]*32 + th*16 + ln] = hb;
            outsC[((size_t)rr0[i]*kS + ssv[i])*kH + th*16 + ln] = (unsigned short)hb;
          }
        }
    }
    lds_barrier();
  }
#undef BFR
}

// ---------------- logits epilogue (fp32 output, unchanged, verified) ----------------
__global__ void logits_kernel(const int* __restrict__ target, const float* __restrict__ wsf,
                              float* __restrict__ out)
{
  int idx = blockIdx.x * 256 + threadIdx.x;
  if (idx >= 3*kB*kR*kS*kV) return;
  int v = idx % kV;
  int pos = idx / kV;
  int g = pos >> 12;
  int ch = g % 3;
  int b = g / 3;
  int rs = pos & 4095;
  const bf16* hv = (const bf16*)wsf + ((size_t)(ch*kB + b)*4096 + rs)*kH;
  float acc;
  const float* wv;
  if (ch == 0) {
    acc = wsf[P_REDB + v];
    wv = wsf + P_REDW + v*kH;
  } else if (ch == 1) {
    int tr = target[(b*3 + 0)*4096 + rs];
    acc = wsf[P_GREENB + v] + wsf[TG_OFF + tr*kV + v];
    wv = wsf + P_GREENW + v*(kH + kE);
  } else {
    int tr = target[(b*3 + 0)*4096 + rs];
    int tg = target[(b*3 + 1)*4096 + rs];
    acc = wsf[P_BLUEB + v] + wsf[TBR_OFF + tr*kV + v] + wsf[TBG_OFF + tg*kV + v];
    wv = wsf + P_BLUEW + v*(kH + 2*kE);
  }
#pragma unroll
  for (int k = 0; k < kH; ++k) acc = fmaf(wv[k], tof(hv[k]), acc);
  out[idx] = acc;
}

extern "C" void kernel_launch(void* const* d_in, const int* in_sizes, int n_in,
                              void* d_out, int out_size, void* d_ws, size_t ws_size,
                              hipStream_t stream)
{
  const int* x      = (const int*)d_in[0];
  const int* target = (const int*)d_in[1];
  float* wsf = (float*)d_ws;

  norm_kernel<<<16, 256, 0, stream>>>(d_in[2], d_in[3], d_in[4], d_in[5], d_in[6], d_in[7],
                                      d_in[8], d_in[9], d_in[10], d_in[11], d_in[12], d_in[13],
                                      d_in[14], d_in[15], d_in[16], d_in[17], wsf);
  const int prepN = 3*kV*kG + 3*kG*kH + 2*kG*kH + 3*kG + 3*kG + 3*kV*kV;
  prep_kernel<<<(prepN + 255)/256, 256, 0, stream>>>(wsf);
  tfold_kernel<<<(3*kV*kG + 255)/256, 256, 0, stream>>>(wsf);
  recur_all_kernel<<<16, 768, 0, stream>>>(x, wsf);
  const int outN = 3*kB*kR*kS*kV;
  logits_kernel<<<(outN + 255)/256, 256, 0, stream>>>(target, wsf, (float*)d_out);
}

// Round 5
// 1890.609 us; speedup vs baseline: 1.7700x; 1.7700x over previous
//
#include <hip/hip_runtime.h>
#include <hip/hip_bf16.h>

using bf16 = __hip_bfloat16;
typedef __attribute__((ext_vector_type(8))) short bfrag;   // 8 bf16 (4 VGPRs)
typedef __attribute__((ext_vector_type(4))) float ffrag;   // 4 fp32 acc

constexpr int kH  = 32;    // hidden
constexpr int kE  = 64;    // embed
constexpr int kV  = 258;   // vocab
constexpr int kB  = 16;    // batch
constexpr int kR  = 64;    // rows
constexpr int kS  = 64;    // cols
constexpr int kG  = 96;    // 3*H
constexpr int kEP = 65;    // E+1

// ---------------- workspace layout (unchanged) ----------------
constexpr int H2_OFF   = (3*kB*kR*kS*kH)/2;
constexpr int PROG_OFF = H2_OFF;                      // 48 ints: channel pipeline progress
constexpr int T_OFF    = H2_OFF + kB*kR*kH;           // [3][258][96]  emb@Wih0[:, :64].T (+bias fold)
constexpr int WPH_OFF  = T_OFF + 3*kV*kG;             // [3][96][32]   Wih0 @ h2e_W  fold
constexpr int WADP_OFF = WPH_OFF + 3*kG*kH;           // [2][96][32]   Wih0 @ adp_W  fold
constexpr int C0_OFF   = WADP_OFF + 2*kG*kH;          // [3][96]
constexpr int RW_OFF   = C0_OFF + 3*kG;               // [3][96]
constexpr int TG_OFF   = RW_OFF + 3*kG;               // [258][258]
constexpr int TBR_OFF  = TG_OFF + kV*kV;              // [258][258]
constexpr int TBG_OFF  = TBR_OFF + kV*kV;             // [258][258]
constexpr int P_EMB    = TBG_OFF + kV*kV;
constexpr int P_WIH0   = P_EMB    + 3*kV*kE;
constexpr int P_WIHR   = P_WIH0   + 3*kG*kEP;
constexpr int P_WHH    = P_WIHR   + 3*2*kG*kH;
constexpr int P_BIH    = P_WHH    + 3*3*kG*kH;
constexpr int P_BHH    = P_BIH    + 3*3*kG;
constexpr int P_H2EW   = P_BHH    + 3*3*kG;
constexpr int P_H2EB   = P_H2EW   + 3*kEP*kH;
constexpr int P_ADPW   = P_H2EB   + 3*kEP;
constexpr int P_ADPB   = P_ADPW   + 2*kEP*kH;
constexpr int P_REDW   = P_ADPB   + 2*kEP;
constexpr int P_REDB   = P_REDW   + kV*kH;
constexpr int P_GREENW = P_REDB   + kV;
constexpr int P_GREENB = P_GREENW + kV*(kH+kE);
constexpr int P_BLUEW  = P_GREENB + kV;
constexpr int P_BLUEB  = P_BLUEW  + kV*(kH+2*kE);
constexpr int WS_END   = P_BLUEB  + kV;               // ~14.0 MB

__device__ __forceinline__ float tof(bf16 h) { return __bfloat162float(h); }

__device__ __forceinline__ unsigned short bfbits(bf16 h) {
  union { bf16 h; unsigned short u; } cv; cv.h = h; return cv.u;
}
__device__ __forceinline__ short f2b(float v) {
  return (short)bfbits(__float2bfloat16(v));
}
__device__ __forceinline__ float sigm(float v) { return 1.0f / (1.0f + __expf(-v)); }
__device__ __forceinline__ float tanh_(float v) { return 1.0f - 2.0f / (__expf(2.0f * v) + 1.0f); }

#define MFMA16(a, bb, cc) __builtin_amdgcn_mfma_f32_16x16x32_bf16((a), (bb), (cc), 0, 0, 0)

// LDS-only barrier: raw s_barrier with lgkmcnt(0) only -- vmem (outs stores,
// T/po prefetch loads) stays in flight across it.
__device__ __forceinline__ void lds_barrier() {
  __builtin_amdgcn_sched_barrier(0);
  asm volatile("s_waitcnt lgkmcnt(0)" ::: "memory");
  __builtin_amdgcn_s_barrier();
  __builtin_amdgcn_sched_barrier(0);
}

// ---------------- dtype detect + normalize to fp32 (unchanged, verified) ----------------
__global__ void norm_kernel(const void* p0, const void* p1, const void* p2, const void* p3,
                            const void* p4, const void* p5, const void* p6, const void* p7,
                            const void* p8, const void* p9, const void* p10, const void* p11,
                            const void* p12, const void* p13, const void* p14, const void* p15,
                            float* __restrict__ wsf)
{
  constexpr int counts[16] = {3*kV*kE, 3*kG*kEP, 3*2*kG*kH, 3*3*kG*kH, 3*3*kG, 3*3*kG,
                              3*kEP*kH, 3*kEP, 2*kEP*kH, 2*kEP, kV*kH, kV,
                              kV*(kH+kE), kV, kV*(kH+2*kE), kV};
  constexpr int dsts[16] = {P_EMB, P_WIH0, P_WIHR, P_WHH, P_BIH, P_BHH,
                            P_H2EW, P_H2EB, P_ADPW, P_ADPB, P_REDW, P_REDB,
                            P_GREENW, P_GREENB, P_BLUEW, P_BLUEB};
  const void* srcs[16] = {p0,p1,p2,p3,p4,p5,p6,p7,p8,p9,p10,p11,p12,p13,p14,p15};

  __shared__ unsigned int smax;
  const int a = blockIdx.x;
  const void* src = srcs[a];
  const int n = counts[a];
  if (threadIdx.x == 0) smax = 0;
  if (a == 0) {
    int* prog = (int*)(wsf + PROG_OFF);
    for (int i = threadIdx.x; i < 48; i += 256) prog[i] = 0;
  }
  __syncthreads();

  const unsigned short* u16 = (const unsigned short*)src;
  const int ns = (n < 2048) ? n : 2048;
  unsigned int lm = 0;
  for (int i = threadIdx.x; i < ns; i += 256) {
    unsigned int e = ((unsigned int)u16[i] >> 7) & 0xFFu;
    if (e > lm) lm = e;
  }
  atomicMax(&smax, lm);
  __syncthreads();

  const bool isf32 = (smax >= 135);
  float* dst = wsf + dsts[a];
  if (isf32) {
    const float* s = (const float*)src;
    for (int i = threadIdx.x; i < n; i += 256) dst[i] = s[i];
  } else {
    const bf16* s = (const bf16*)src;
    for (int i = threadIdx.x; i < n; i += 256) dst[i] = tof(s[i]);
  }
}

// ---------------- prep: fold tables & matrices (unchanged, verified) ----------------
__global__ void prep_kernel(float* __restrict__ wsf)
{
  int idx = blockIdx.x * 256 + threadIdx.x;

  if (idx < 3*kV*kG) {
    int c = idx / (kV*kG);
    int rem = idx - c*(kV*kG);
    int v = rem / kG;
    int j = rem - v*kG;
    const float* ev = wsf + P_EMB + (c*kV + v)*kE;
    const float* wr = wsf + P_WIH0 + (c*kG + j)*kEP;
    float acc = 0.f;
    for (int e = 0; e < kE; ++e) acc = fmaf(ev[e], wr[e], acc);
    wsf[T_OFF + idx] = acc;
    return;
  }
  idx -= 3*kV*kG;

  if (idx < 3*kG*kH) {
    int c = idx / (kG*kH);
    int rem = idx - c*(kG*kH);
    int j = rem >> 5;
    int k = rem & 31;
    const float* wr = wsf + P_WIH0 + (c*kG + j)*kEP;
    const float* hw = wsf + P_H2EW + c*kEP*kH + k;
    float acc = 0.f;
    for (int e = 0; e < kEP; ++e) acc = fmaf(wr[e], hw[e*kH], acc);
    wsf[WPH_OFF + idx] = acc;
    return;
  }
  idx -= 3*kG*kH;

  if (idx < 2*kG*kH) {
    int cm = idx / (kG*kH);
    int rem = idx - cm*(kG*kH);
    int j = rem >> 5;
    int k = rem & 31;
    const float* wr = wsf + P_WIH0 + ((cm+1)*kG + j)*kEP;
    const float* aw = wsf + P_ADPW + cm*kEP*kH + k;
    float acc = 0.f;
    for (int e = 0; e < kEP; ++e) acc = fmaf(wr[e], aw[e*kH], acc);
    wsf[WADP_OFF + idx] = acc;
    return;
  }
  idx -= 2*kG*kH;

  if (idx < 3*kG) {
    int c = idx / kG;
    int j = idx - c*kG;
    const float* wr = wsf + P_WIH0 + (c*kG + j)*kEP;
    float acc = wsf[P_BIH + (c*3 + 0)*kG + j];
    for (int e = 0; e < kEP; ++e) acc = fmaf(wsf[P_H2EB + c*kEP + e], wr[e], acc);
    if (c > 0)
      for (int e = 0; e < kEP; ++e) acc = fmaf(wsf[P_ADPB + (c-1)*kEP + e], wr[e], acc);
    wsf[C0_OFF + idx] = acc;
    return;
  }
  idx -= 3*kG;

  if (idx < 3*kG) {
    int c = idx / kG;
    int j = idx - c*kG;
    wsf[RW_OFF + idx] = wsf[P_WIH0 + (c*kG + j)*kEP + kE];
    return;
  }
  idx -= 3*kG;

  if (idx < kV*kV) {
    int v = idx / kV, w = idx - (idx / kV)*kV;
    const float* ev = wsf + P_EMB + v*kE;
    const float* gw = wsf + P_GREENW + w*(kH + kE) + kH;
    float acc = 0.f;
    for (int e = 0; e < kE; ++e) acc = fmaf(ev[e], gw[e], acc);
    wsf[TG_OFF + idx] = acc;
    return;
  }
  idx -= kV*kV;

  if (idx < kV*kV) {
    int v = idx / kV, w = idx - (idx / kV)*kV;
    const float* ev = wsf + P_EMB + v*kE;
    const float* bw = wsf + P_BLUEW + w*(kH + 2*kE) + kH;
    float acc = 0.f;
    for (int e = 0; e < kE; ++e) acc = fmaf(ev[e], bw[e], acc);
    wsf[TBR_OFF + idx] = acc;
    return;
  }
  idx -= kV*kV;

  if (idx < kV*kV) {
    int v = idx / kV, w = idx - (idx / kV)*kV;
    const float* ev = wsf + P_EMB + (kV + v)*kE;
    const float* bw = wsf + P_BLUEW + w*(kH + 2*kE) + kH + kE;
    float acc = 0.f;
    for (int e = 0; e < kE; ++e) acc = fmaf(ev[e], bw[e], acc);
    wsf[TBG_OFF + idx] = acc;
  }
}

// ---------------- fold layer-0 gate constants into T (verified round 4) ----------------
__global__ void tfold_kernel(float* __restrict__ wsf)
{
  int idx = blockIdx.x * 256 + threadIdx.x;
  if (idx >= 3*kV*kG) return;
  int c = idx / (kV*kG);
  int g = idx % kG;
  float add = wsf[C0_OFF + c*kG + g];
  if (g < 2*kH) add += wsf[P_BHH + (c*3 + 0)*kG + g];
  wsf[T_OFF + idx] += add;
}

// ---------------- fused 3-channel MFMA wavefront recurrence ----------------
// Round-4 lesson: any config capping VGPR < weights(168)+state spills the
// loop-invariant weight frags to scratch (VGPR_Count=84, +10MB HBM traffic).
// Back to the round-0 shape -- 48 WGs (wg = c*16+b), 4 waves x 16 rows,
// __launch_bounds__(256,1) => VGPR cap 512, all 7 weight mats in registers,
// NO spill (R0 measured 248 VGPR) -- plus the chain-shorteners verified in R4:
//   - lds_barrier (lgkmcnt-only) for both per-step barriers
//   - T-gather prefetched one diagonal ahead, T-add moved post-MFMA
//   - NEW: producer outs (po) prefetched one diagonal ahead (cross-XCD read
//     leaves the chain head); DELTA=4 gives the flag handshake 2 steps slack;
//     flag release deferred to next step start (covered by pre-barB drain).
__global__ __launch_bounds__(256, 1)
void recur_all_kernel(const int* __restrict__ x, float* __restrict__ wsf)
{
  __shared__ __align__(16) short RING[2][kR][kH];   // layer-2 outs, slot = diag&1
  __shared__ __align__(16) short H0L[kR][kH];
  __shared__ __align__(16) short H1L[kR][kH];

  const int wg = blockIdx.x;
  const int c  = wg >> 4;
  const int b  = wg & 15;
  const int tid = threadIdx.x;
  const int w    = tid >> 6;        // wave id: 16-row band
  const int lane = tid & 63;
  const int m    = lane & 15;
  const int q    = lane >> 4;
  const int ln   = m;
  const int cb0  = w * 16;

  for (int i = tid; i < 2*kR*kH; i += 256) (&RING[0][0][0])[i] = 0;
  for (int i = tid; i < kR*kH;   i += 256) (&H0L[0][0])[i] = 0;
  for (int i = tid; i < kR*kH;   i += 256) (&H1L[0][0])[i] = 0;

  // ---- 7 weight matrices as register B-fragments (168 VGPRs, no cap => no spill) ----
  // 0:Wph 1:Whh0 2:Wih1 3:Whh1 4:Wih2 5:Whh2 6:Wadp
  const float* wsrc[7];
  wsrc[0] = wsf + WPH_OFF + c*kG*kH;
  wsrc[1] = wsf + P_WHH  + (c*3+0)*kG*kH;
  wsrc[2] = wsf + P_WIHR + (c*2+0)*kG*kH;
  wsrc[3] = wsf + P_WHH  + (c*3+1)*kG*kH;
  wsrc[4] = wsf + P_WIHR + (c*2+1)*kG*kH;
  wsrc[5] = wsf + P_WHH  + (c*3+2)*kG*kH;
  wsrc[6] = (c > 0) ? (wsf + WADP_OFF + (c-1)*kG*kH) : (wsf + WPH_OFF);
  bfrag Wb[7][6];
#pragma unroll
  for (int mt = 0; mt < 7; ++mt) {
#pragma unroll
    for (int u = 0; u < 6; ++u) {
      const float* p = wsrc[mt] + (u*16 + ln)*kH + q*8;
#pragma unroll
      for (int j = 0; j < 8; ++j) Wb[mt][u][j] = f2b(p[j]);
    }
  }

  // ---- per-lane gate constants (layer-0 c0/bias folded into T by tfold) ----
  float rwt[6], bh0n[2], bi1z[4], bi1n[2], bh1n[2], bi2z[4], bi2n[2], bh2n[2];
#pragma unroll
  for (int u = 0; u < 6; ++u) rwt[u] = wsf[RW_OFF + c*kG + u*16 + ln];
#pragma unroll
  for (int u = 0; u < 4; ++u) {
    int g = u*16 + ln;
    bi1z[u] = wsf[P_BIH + (c*3+1)*kG + g] + wsf[P_BHH + (c*3+1)*kG + g];
    bi2z[u] = wsf[P_BIH + (c*3+2)*kG + g] + wsf[P_BHH + (c*3+2)*kG + g];
  }
#pragma unroll
  for (int t2 = 0; t2 < 2; ++t2) {
    int g = 64 + t2*16 + ln;
    bh0n[t2] = wsf[P_BHH + (c*3+0)*kG + g];
    bi1n[t2] = wsf[P_BIH + (c*3+1)*kG + g];
    bh1n[t2] = wsf[P_BHH + (c*3+1)*kG + g];
    bi2n[t2] = wsf[P_BIH + (c*3+2)*kG + g];
    bh2n[t2] = wsf[P_BHH + (c*3+2)*kG + g];
  }

  float h0s[8], h1s[8], h2s[8];
#pragma unroll
  for (int i = 0; i < 8; ++i) { h0s[i] = 0.f; h1s[i] = 0.f; h2s[i] = 0.f; }

  unsigned short* outsAll = (unsigned short*)wsf;
  unsigned short* outsC = outsAll + (size_t)(c*kB + b) * (kR*kS*kH);
  const unsigned short* outsP = outsAll + (size_t)(((c > 0 ? c : 1) - 1)*kB + b) * (kR*kS*kH);
  int* prog = (int*)(wsf + PROG_OFF);
  const int* xc = x + (b*3 + c) * kR * kS;
  const float* Tc = wsf + T_OFF + (size_t)c * kV * kG;

  int rr0[4]; float rpw[4];
#pragma unroll
  for (int i = 0; i < 4; ++i) {
    rr0[i] = cb0 + q*4 + i;
    rpw[i] = (float)rr0[i] * (2.0f/64.0f) - 1.0f;
  }

  // ---- prefetch state: T values and producer-outs fragment, one diag ahead ----
  float tv[6][4];
  bfrag poPre;
  auto load_tv = [&](int dd) {
#pragma unroll
    for (int i = 0; i < 4; ++i) {
      int sv = dd - rr0[i];
      int scl = sv < 0 ? 0 : (sv > 63 ? 63 : sv);
      int xiv = xc[rr0[i]*kS + scl];
      const float* tp = Tc + (size_t)xiv*kG;
#pragma unroll
      for (int u = 0; u < 6; ++u) tv[u][i] = tp[u*16 + ln];
    }
  };
  auto load_po = [&](int dd) {
    int sv = dd - (cb0 + m);
    int scl = sv < 0 ? 0 : (sv > 63 ? 63 : sv);
    poPre = *(const bfrag*)&outsP[((size_t)(cb0 + m)*kS + scl)*kH + q*8];
  };
  load_tv(cb0);           // safe pre-loop: T is static
#pragma unroll
  for (int j = 0; j < 8; ++j) poPre[j] = 0;   // first real po load happens in-loop, gated by prog

  __syncthreads();

  constexpr int DELTA = 4;
  constexpr int TT = (kR + kS - 1) + 2*DELTA;   // 135
  for (int t = 0; t < TT; ++t) {
    const int d = t - c*DELTA;

    // phase 1 (tid0): release prev diagonal (stores drained pre-barB last step),
    // then acquire producer progress needed for THIS step's po prefetch (d+1).
    if (tid == 0) {
      if (c < 2 && d >= 1 && d <= 127)
        __hip_atomic_store(&prog[c*16 + b], d, __ATOMIC_RELEASE, __HIP_MEMORY_SCOPE_AGENT);
      if (c > 0 && d >= -1 && d <= 125) {
        const int need = d + 2;
        while (__hip_atomic_load(&prog[(c-1)*16 + b], __ATOMIC_ACQUIRE,
                                 __HIP_MEMORY_SCOPE_AGENT) < need) { }
      }
    }
    lds_barrier();   // barA: progress + ring(d-1) visible WG-wide

    const bool activ = (d >= cb0) && (d <= cb0 + 78);
    if (activ) {
      const int ps = (d - 1) & 1;
      const int cs = d & 1;

      int ssv[4];
      bool act[4];
#pragma unroll
      for (int i = 0; i < 4; ++i) {
        ssv[i] = d - rr0[i];
        act[i] = ((unsigned)ssv[i]) < 64u;
      }
      const int row = cb0 + m;

      bfrag phA, h0A;
      {
        int pr = row - 1;
        int prc = pr < 0 ? 0 : pr;
        phA = *(const bfrag*)&RING[ps][prc][q*8];
        if (pr < 0) {
#pragma unroll
          for (int j = 0; j < 8; ++j) phA[j] = 0;
        }
        h0A = *(const bfrag*)&H0L[row][q*8];
      }
      bfrag poA = poPre;   // prefetched last iteration

      // ---- layer 0: zero-init, MFMA chain, T-add after (R4-verified) ----
      ffrag rz[4], gn[2], hn[2];
#pragma unroll
      for (int u = 0; u < 4; ++u)
#pragma unroll
        for (int i = 0; i < 4; ++i) rz[u][i] = 0.f;
#pragma unroll
      for (int t2 = 0; t2 < 2; ++t2)
#pragma unroll
        for (int i = 0; i < 4; ++i) { gn[t2][i] = 0.f; hn[t2][i] = bh0n[t2]; }

#pragma unroll
      for (int u = 0; u < 4; ++u)
        rz[u] = MFMA16(phA, Wb[0][u], rz[u]);
#pragma unroll
      for (int t2 = 0; t2 < 2; ++t2)
        gn[t2] = MFMA16(phA, Wb[0][4+t2], gn[t2]);
      if (c > 0) {
#pragma unroll
        for (int u = 0; u < 4; ++u)
          rz[u] = MFMA16(poA, Wb[6][u], rz[u]);
#pragma unroll
        for (int t2 = 0; t2 < 2; ++t2)
          gn[t2] = MFMA16(poA, Wb[6][4+t2], gn[t2]);
      }
#pragma unroll
      for (int u = 0; u < 4; ++u)
        rz[u] = MFMA16(h0A, Wb[1][u], rz[u]);
#pragma unroll
      for (int t2 = 0; t2 < 2; ++t2)
        hn[t2] = MFMA16(h0A, Wb[1][4+t2], hn[t2]);

      // consume prefetched T (garbage lanes masked by act)
#pragma unroll
      for (int u = 0; u < 4; ++u)
#pragma unroll
        for (int i = 0; i < 4; ++i) rz[u][i] += tv[u][i] + rpw[i]*rwt[u];
#pragma unroll
      for (int t2 = 0; t2 < 2; ++t2)
#pragma unroll
        for (int i = 0; i < 4; ++i) gn[t2][i] += tv[4+t2][i] + rpw[i]*rwt[4+t2];

      // issue next-step prefetches EARLY so they age across layers 1-2
      if (d + 1 <= cb0 + 78) {
        load_tv(d + 1);
        if (c > 0) load_po(d + 1);
      }

#pragma unroll
      for (int i = 0; i < 4; ++i)
#pragma unroll
        for (int th = 0; th < 2; ++th) {
          float rg = sigm(rz[th][i]);
          float zg = sigm(rz[2+th][i]);
          float ng = tanh_(gn[th][i] + rg*hn[th][i]);
          float h0v = (1.f - zg)*ng + zg*h0s[i*2+th];
          if (act[i]) {
            h0s[i*2+th] = h0v;
            H0L[rr0[i]][th*16 + ln] = f2b(h0v);
          }
        }
      bfrag h0An = *(const bfrag*)&H0L[row][q*8];

      // ---- layer 1 ----
      bfrag h1A = *(const bfrag*)&H1L[row][q*8];
      ffrag rz1[4], gn1[2], hn1[2];
#pragma unroll
      for (int u = 0; u < 4; ++u)
#pragma unroll
        for (int i = 0; i < 4; ++i) rz1[u][i] = bi1z[u];
#pragma unroll
      for (int t2 = 0; t2 < 2; ++t2)
#pragma unroll
        for (int i = 0; i < 4; ++i) { gn1[t2][i] = bi1n[t2]; hn1[t2][i] = bh1n[t2]; }
#pragma unroll
      for (int u = 0; u < 4; ++u) {
        rz1[u] = MFMA16(h0An, Wb[2][u], rz1[u]);
        rz1[u] = MFMA16(h1A,  Wb[3][u], rz1[u]);
      }
#pragma unroll
      for (int t2 = 0; t2 < 2; ++t2) {
        gn1[t2] = MFMA16(h0An, Wb[2][4+t2], gn1[t2]);
        hn1[t2] = MFMA16(h1A,  Wb[3][4+t2], hn1[t2]);
      }
#pragma unroll
      for (int i = 0; i < 4; ++i)
#pragma unroll
        for (int th = 0; th < 2; ++th) {
          float rg = sigm(rz1[th][i]);
          float zg = sigm(rz1[2+th][i]);
          float ng = tanh_(gn1[th][i] + rg*hn1[th][i]);
          float h1v = (1.f - zg)*ng + zg*h1s[i*2+th];
          if (act[i]) {
            h1s[i*2+th] = h1v;
            H1L[rr0[i]][th*16 + ln] = f2b(h1v);
          }
        }
      bfrag h1An = *(const bfrag*)&H1L[row][q*8];

      // ---- layer 2 ----
      bfrag h2A = *(const bfrag*)&RING[ps][row][q*8];
      if (m == d - cb0) {            // s==0 row: no left neighbor
#pragma unroll
        for (int j = 0; j < 8; ++j) h2A[j] = 0;
      }
      ffrag rz2[4], gn2[2], hn2[2];
#pragma unroll
      for (int u = 0; u < 4; ++u)
#pragma unroll
        for (int i = 0; i < 4; ++i) rz2[u][i] = bi2z[u];
#pragma unroll
      for (int t2 = 0; t2 < 2; ++t2)
#pragma unroll
        for (int i = 0; i < 4; ++i) { gn2[t2][i] = bi2n[t2]; hn2[t2][i] = bh2n[t2]; }
#pragma unroll
      for (int u = 0; u < 4; ++u) {
        rz2[u] = MFMA16(h1An, Wb[4][u], rz2[u]);
        rz2[u] = MFMA16(h2A,  Wb[5][u], rz2[u]);
      }
#pragma unroll
      for (int t2 = 0; t2 < 2; ++t2) {
        gn2[t2] = MFMA16(h1An, Wb[4][4+t2], gn2[t2]);
        hn2[t2] = MFMA16(h2A,  Wb[5][4+t2], hn2[t2]);
      }
#pragma unroll
      for (int i = 0; i < 4; ++i)
#pragma unroll
        for (int th = 0; th < 2; ++th) {
          float rg = sigm(rz2[th][i]);
          float zg = sigm(rz2[2+th][i]);
          float ng = tanh_(gn2[th][i] + rg*hn2[th][i]);
          float h2old = (ssv[i] == 0) ? 0.f : h2s[i*2+th];
          float h2v = (1.f - zg)*ng + zg*h2old;
          if (act[i]) {
            h2s[i*2+th] = h2v;
            short hb = f2b(h2v);
            RING[cs][rr0[i]][th*16 + ln] = hb;
            outsC[((size_t)rr0[i]*kS + ssv[i])*kH + th*16 + ln] = (unsigned short)hb;
          }
        }
    } else {
      // prologue iterations: issue prefetches for this wave's first diagonal
      if (d + 1 >= cb0 && d + 1 <= cb0 + 78) {
        load_tv(d + 1);
        if (c > 0) load_po(d + 1);
      }
    }

    // producers: drain own vmem (stores fresh ~400cyc; prefetch loads aged)
    // so next step's tid0 release covers all threads' outs stores.
    if (c < 2) {
      __builtin_amdgcn_sched_barrier(0);
      asm volatile("s_waitcnt vmcnt(0)" ::: "memory");
    }
    lds_barrier();   // barB: ring(d)+H01(d) visible for next diagonal
  }
}

// ---------------- logits epilogue (fp32 output, unchanged, verified) ----------------
__global__ void logits_kernel(const int* __restrict__ target, const float* __restrict__ wsf,
                              float* __restrict__ out)
{
  int idx = blockIdx.x * 256 + threadIdx.x;
  if (idx >= 3*kB*kR*kS*kV) return;
  int v = idx % kV;
  int pos = idx / kV;
  int g = pos >> 12;
  int ch = g % 3;
  int b = g / 3;
  int rs = pos & 4095;
  const bf16* hv = (const bf16*)wsf + ((size_t)(ch*kB + b)*4096 + rs)*kH;
  float acc;
  const float* wv;
  if (ch == 0) {
    acc = wsf[P_REDB + v];
    wv = wsf + P_REDW + v*kH;
  } else if (ch == 1) {
    int tr = target[(b*3 + 0)*4096 + rs];
    acc = wsf[P_GREENB + v] + wsf[TG_OFF + tr*kV + v];
    wv = wsf + P_GREENW + v*(kH + kE);
  } else {
    int tr = target[(b*3 + 0)*4096 + rs];
    int tg = target[(b*3 + 1)*4096 + rs];
    acc = wsf[P_BLUEB + v] + wsf[TBR_OFF + tr*kV + v] + wsf[TBG_OFF + tg*kV + v];
    wv = wsf + P_BLUEW + v*(kH + 2*kE);
  }
#pragma unroll
  for (int k = 0; k < kH; ++k) acc = fmaf(wv[k], tof(hv[k]), acc);
  out[idx] = acc;
}

extern "C" void kernel_launch(void* const* d_in, const int* in_sizes, int n_in,
                              void* d_out, int out_size, void* d_ws, size_t ws_size,
                              hipStream_t stream)
{
  const int* x      = (const int*)d_in[0];
  const int* target = (const int*)d_in[1];
  float* wsf = (float*)d_ws;

  norm_kernel<<<16, 256, 0, stream>>>(d_in[2], d_in[3], d_in[4], d_in[5], d_in[6], d_in[7],
                                      d_in[8], d_in[9], d_in[10], d_in[11], d_in[12], d_in[13],
                                      d_in[14], d_in[15], d_in[16], d_in[17], wsf);
  const int prepN = 3*kV*kG + 3*kG*kH + 2*kG*kH + 3*kG + 3*kG + 3*kV*kV;
  prep_kernel<<<(prepN + 255)/256, 256, 0, stream>>>(wsf);
  tfold_kernel<<<(3*kV*kG + 255)/256, 256, 0, stream>>>(wsf);
  recur_all_kernel<<<48, 256, 0, stream>>>(x, wsf);
  const int outN = 3*kB*kR*kS*kV;
  logits_kernel<<<(outN + 255)/256, 256, 0, stream>>>(target, wsf, (float*)d_out);
}

// Round 6
// 1197.439 us; speedup vs baseline: 2.7946x; 1.5789x over previous
//
#include <hip/hip_runtime.h>
#include <hip/hip_bf16.h>

using bf16 = __hip_bfloat16;
typedef __attribute__((ext_vector_type(8))) short bfrag;   // 8 bf16 (4 VGPRs)
typedef __attribute__((ext_vector_type(4))) float ffrag;   // 4 fp32 acc

constexpr int kH  = 32;    // hidden
constexpr int kE  = 64;    // embed
constexpr int kV  = 258;   // vocab
constexpr int kB  = 16;    // batch
constexpr int kR  = 64;    // rows
constexpr int kS  = 64;    // cols
constexpr int kG  = 96;    // 3*H
constexpr int kEP = 65;    // E+1

// ---------------- workspace layout (unchanged) ----------------
constexpr int H2_OFF   = (3*kB*kR*kS*kH)/2;
constexpr int PROG_OFF = H2_OFF;                      // 48 ints: channel pipeline progress
constexpr int T_OFF    = H2_OFF + kB*kR*kH;           // [3][258][96]  emb@Wih0[:, :64].T (+bias fold)
constexpr int WPH_OFF  = T_OFF + 3*kV*kG;             // [3][96][32]   Wih0 @ h2e_W  fold
constexpr int WADP_OFF = WPH_OFF + 3*kG*kH;           // [2][96][32]   Wih0 @ adp_W  fold
constexpr int C0_OFF   = WADP_OFF + 2*kG*kH;          // [3][96]
constexpr int RW_OFF   = C0_OFF + 3*kG;               // [3][96]
constexpr int TG_OFF   = RW_OFF + 3*kG;               // [258][258]
constexpr int TBR_OFF  = TG_OFF + kV*kV;              // [258][258]
constexpr int TBG_OFF  = TBR_OFF + kV*kV;             // [258][258]
constexpr int P_EMB    = TBG_OFF + kV*kV;
constexpr int P_WIH0   = P_EMB    + 3*kV*kE;
constexpr int P_WIHR   = P_WIH0   + 3*kG*kEP;
constexpr int P_WHH    = P_WIHR   + 3*2*kG*kH;
constexpr int P_BIH    = P_WHH    + 3*3*kG*kH;
constexpr int P_BHH    = P_BIH    + 3*3*kG;
constexpr int P_H2EW   = P_BHH    + 3*3*kG;
constexpr int P_H2EB   = P_H2EW   + 3*kEP*kH;
constexpr int P_ADPW   = P_H2EB   + 3*kEP;
constexpr int P_ADPB   = P_ADPW   + 2*kEP*kH;
constexpr int P_REDW   = P_ADPB   + 2*kEP;
constexpr int P_REDB   = P_REDW   + kV*kH;
constexpr int P_GREENW = P_REDB   + kV;
constexpr int P_GREENB = P_GREENW + kV*(kH+kE);
constexpr int P_BLUEW  = P_GREENB + kV;
constexpr int P_BLUEB  = P_BLUEW  + kV*(kH+2*kE);
constexpr int WS_END   = P_BLUEB  + kV;               // ~14.0 MB

__device__ __forceinline__ float tof(bf16 h) { return __bfloat162float(h); }

__device__ __forceinline__ unsigned short bfbits(bf16 h) {
  union { bf16 h; unsigned short u; } cv; cv.h = h; return cv.u;
}
__device__ __forceinline__ short f2b(float v) {
  return (short)bfbits(__float2bfloat16(v));
}
__device__ __forceinline__ float b2f(short s) {
  union { unsigned short u; } cv; cv.u = (unsigned short)s;
  bf16 h; __builtin_memcpy(&h, &cv.u, 2); return __bfloat162float(h);
}
__device__ __forceinline__ float sigm(float v) { return 1.0f / (1.0f + __expf(-v)); }
__device__ __forceinline__ float tanh_(float v) { return 1.0f - 2.0f / (__expf(2.0f * v) + 1.0f); }

#define MFMA16(a, bb, cc) __builtin_amdgcn_mfma_f32_16x16x32_bf16((a), (bb), (cc), 0, 0, 0)

// LDS-only barrier: raw s_barrier with lgkmcnt(0) only -- vmem (outs stores,
// T/po prefetch loads) stays in flight across it.
__device__ __forceinline__ void lds_barrier() {
  __builtin_amdgcn_sched_barrier(0);
  asm volatile("s_waitcnt lgkmcnt(0)" ::: "memory");
  __builtin_amdgcn_s_barrier();
  __builtin_amdgcn_sched_barrier(0);
}

// ---------------- dtype detect + normalize to fp32 (unchanged, verified) ----------------
__global__ void norm_kernel(const void* p0, const void* p1, const void* p2, const void* p3,
                            const void* p4, const void* p5, const void* p6, const void* p7,
                            const void* p8, const void* p9, const void* p10, const void* p11,
                            const void* p12, const void* p13, const void* p14, const void* p15,
                            float* __restrict__ wsf)
{
  constexpr int counts[16] = {3*kV*kE, 3*kG*kEP, 3*2*kG*kH, 3*3*kG*kH, 3*3*kG, 3*3*kG,
                              3*kEP*kH, 3*kEP, 2*kEP*kH, 2*kEP, kV*kH, kV,
                              kV*(kH+kE), kV, kV*(kH+2*kE), kV};
  constexpr int dsts[16] = {P_EMB, P_WIH0, P_WIHR, P_WHH, P_BIH, P_BHH,
                            P_H2EW, P_H2EB, P_ADPW, P_ADPB, P_REDW, P_REDB,
                            P_GREENW, P_GREENB, P_BLUEW, P_BLUEB};
  const void* srcs[16] = {p0,p1,p2,p3,p4,p5,p6,p7,p8,p9,p10,p11,p12,p13,p14,p15};

  __shared__ unsigned int smax;
  const int a = blockIdx.x;
  const void* src = srcs[a];
  const int n = counts[a];
  if (threadIdx.x == 0) smax = 0;
  if (a == 0) {
    int* prog = (int*)(wsf + PROG_OFF);
    for (int i = threadIdx.x; i < 48; i += 256) prog[i] = 0;
  }
  __syncthreads();

  const unsigned short* u16 = (const unsigned short*)src;
  const int ns = (n < 2048) ? n : 2048;
  unsigned int lm = 0;
  for (int i = threadIdx.x; i < ns; i += 256) {
    unsigned int e = ((unsigned int)u16[i] >> 7) & 0xFFu;
    if (e > lm) lm = e;
  }
  atomicMax(&smax, lm);
  __syncthreads();

  const bool isf32 = (smax >= 135);
  float* dst = wsf + dsts[a];
  if (isf32) {
    const float* s = (const float*)src;
    for (int i = threadIdx.x; i < n; i += 256) dst[i] = s[i];
  } else {
    const bf16* s = (const bf16*)src;
    for (int i = threadIdx.x; i < n; i += 256) dst[i] = tof(s[i]);
  }
}

// ---------------- prep: fold tables & matrices (unchanged, verified) ----------------
__global__ void prep_kernel(float* __restrict__ wsf)
{
  int idx = blockIdx.x * 256 + threadIdx.x;

  if (idx < 3*kV*kG) {
    int c = idx / (kV*kG);
    int rem = idx - c*(kV*kG);
    int v = rem / kG;
    int j = rem - v*kG;
    const float* ev = wsf + P_EMB + (c*kV + v)*kE;
    const float* wr = wsf + P_WIH0 + (c*kG + j)*kEP;
    float acc = 0.f;
    for (int e = 0; e < kE; ++e) acc = fmaf(ev[e], wr[e], acc);
    wsf[T_OFF + idx] = acc;
    return;
  }
  idx -= 3*kV*kG;

  if (idx < 3*kG*kH) {
    int c = idx / (kG*kH);
    int rem = idx - c*(kG*kH);
    int j = rem >> 5;
    int k = rem & 31;
    const float* wr = wsf + P_WIH0 + (c*kG + j)*kEP;
    const float* hw = wsf + P_H2EW + c*kEP*kH + k;
    float acc = 0.f;
    for (int e = 0; e < kEP; ++e) acc = fmaf(wr[e], hw[e*kH], acc);
    wsf[WPH_OFF + idx] = acc;
    return;
  }
  idx -= 3*kG*kH;

  if (idx < 2*kG*kH) {
    int cm = idx / (kG*kH);
    int rem = idx - cm*(kG*kH);
    int j = rem >> 5;
    int k = rem & 31;
    const float* wr = wsf + P_WIH0 + ((cm+1)*kG + j)*kEP;
    const float* aw = wsf + P_ADPW + cm*kEP*kH + k;
    float acc = 0.f;
    for (int e = 0; e < kEP; ++e) acc = fmaf(wr[e], aw[e*kH], acc);
    wsf[WADP_OFF + idx] = acc;
    return;
  }
  idx -= 2*kG*kH;

  if (idx < 3*kG) {
    int c = idx / kG;
    int j = idx - c*kG;
    const float* wr = wsf + P_WIH0 + (c*kG + j)*kEP;
    float acc = wsf[P_BIH + (c*3 + 0)*kG + j];
    for (int e = 0; e < kEP; ++e) acc = fmaf(wsf[P_H2EB + c*kEP + e], wr[e], acc);
    if (c > 0)
      for (int e = 0; e < kEP; ++e) acc = fmaf(wsf[P_ADPB + (c-1)*kEP + e], wr[e], acc);
    wsf[C0_OFF + idx] = acc;
    return;
  }
  idx -= 3*kG;

  if (idx < 3*kG) {
    int c = idx / kG;
    int j = idx - c*kG;
    wsf[RW_OFF + idx] = wsf[P_WIH0 + (c*kG + j)*kEP + kE];
    return;
  }
  idx -= 3*kG;

  if (idx < kV*kV) {
    int v = idx / kV, w = idx - (idx / kV)*kV;
    const float* ev = wsf + P_EMB + v*kE;
    const float* gw = wsf + P_GREENW + w*(kH + kE) + kH;
    float acc = 0.f;
    for (int e = 0; e < kE; ++e) acc = fmaf(ev[e], gw[e], acc);
    wsf[TG_OFF + idx] = acc;
    return;
  }
  idx -= kV*kV;

  if (idx < kV*kV) {
    int v = idx / kV, w = idx - (idx / kV)*kV;
    const float* ev = wsf + P_EMB + v*kE;
    const float* bw = wsf + P_BLUEW + w*(kH + 2*kE) + kH;
    float acc = 0.f;
    for (int e = 0; e < kE; ++e) acc = fmaf(ev[e], bw[e], acc);
    wsf[TBR_OFF + idx] = acc;
    return;
  }
  idx -= kV*kV;

  if (idx < kV*kV) {
    int v = idx / kV, w = idx - (idx / kV)*kV;
    const float* ev = wsf + P_EMB + (kV + v)*kE;
    const float* bw = wsf + P_BLUEW + w*(kH + 2*kE) + kH + kE;
    float acc = 0.f;
    for (int e = 0; e < kE; ++e) acc = fmaf(ev[e], bw[e], acc);
    wsf[TBG_OFF + idx] = acc;
  }
}

// ---------------- fold layer-0 gate constants into T (verified round 4) ----------------
__global__ void tfold_kernel(float* __restrict__ wsf)
{
  int idx = blockIdx.x * 256 + threadIdx.x;
  if (idx >= 3*kV*kG) return;
  int c = idx / (kV*kG);
  int g = idx % kG;
  float add = wsf[C0_OFF + c*kG + g];
  if (g < 2*kH) add += wsf[P_BHH + (c*3 + 0)*kG + g];
  wsf[T_OFF + idx] += add;
}

// ---------------- fused 3-channel MFMA wavefront recurrence (verified round 5) ----------
// 48 WGs (wg = c*16+b), 4 waves x 16 rows, __launch_bounds__(256,1) => VGPR cap 512,
// all 7 weight mats in registers (no spill); lds_barrier (lgkmcnt-only); T-gather and
// producer-outs prefetched one diagonal ahead; T-add post-MFMA; DELTA=4 handshake.
__global__ __launch_bounds__(256, 1)
void recur_all_kernel(const int* __restrict__ x, float* __restrict__ wsf)
{
  __shared__ __align__(16) short RING[2][kR][kH];   // layer-2 outs, slot = diag&1
  __shared__ __align__(16) short H0L[kR][kH];
  __shared__ __align__(16) short H1L[kR][kH];

  const int wg = blockIdx.x;
  const int c  = wg >> 4;
  const int b  = wg & 15;
  const int tid = threadIdx.x;
  const int w    = tid >> 6;        // wave id: 16-row band
  const int lane = tid & 63;
  const int m    = lane & 15;
  const int q    = lane >> 4;
  const int ln   = m;
  const int cb0  = w * 16;

  for (int i = tid; i < 2*kR*kH; i += 256) (&RING[0][0][0])[i] = 0;
  for (int i = tid; i < kR*kH;   i += 256) (&H0L[0][0])[i] = 0;
  for (int i = tid; i < kR*kH;   i += 256) (&H1L[0][0])[i] = 0;

  // ---- 7 weight matrices as register B-fragments (168 VGPRs, no cap => no spill) ----
  // 0:Wph 1:Whh0 2:Wih1 3:Whh1 4:Wih2 5:Whh2 6:Wadp
  const float* wsrc[7];
  wsrc[0] = wsf + WPH_OFF + c*kG*kH;
  wsrc[1] = wsf + P_WHH  + (c*3+0)*kG*kH;
  wsrc[2] = wsf + P_WIHR + (c*2+0)*kG*kH;
  wsrc[3] = wsf + P_WHH  + (c*3+1)*kG*kH;
  wsrc[4] = wsf + P_WIHR + (c*2+1)*kG*kH;
  wsrc[5] = wsf + P_WHH  + (c*3+2)*kG*kH;
  wsrc[6] = (c > 0) ? (wsf + WADP_OFF + (c-1)*kG*kH) : (wsf + WPH_OFF);
  bfrag Wb[7][6];
#pragma unroll
  for (int mt = 0; mt < 7; ++mt) {
#pragma unroll
    for (int u = 0; u < 6; ++u) {
      const float* p = wsrc[mt] + (u*16 + ln)*kH + q*8;
#pragma unroll
      for (int j = 0; j < 8; ++j) Wb[mt][u][j] = f2b(p[j]);
    }
  }

  // ---- per-lane gate constants (layer-0 c0/bias folded into T by tfold) ----
  float rwt[6], bh0n[2], bi1z[4], bi1n[2], bh1n[2], bi2z[4], bi2n[2], bh2n[2];
#pragma unroll
  for (int u = 0; u < 6; ++u) rwt[u] = wsf[RW_OFF + c*kG + u*16 + ln];
#pragma unroll
  for (int u = 0; u < 4; ++u) {
    int g = u*16 + ln;
    bi1z[u] = wsf[P_BIH + (c*3+1)*kG + g] + wsf[P_BHH + (c*3+1)*kG + g];
    bi2z[u] = wsf[P_BIH + (c*3+2)*kG + g] + wsf[P_BHH + (c*3+2)*kG + g];
  }
#pragma unroll
  for (int t2 = 0; t2 < 2; ++t2) {
    int g = 64 + t2*16 + ln;
    bh0n[t2] = wsf[P_BHH + (c*3+0)*kG + g];
    bi1n[t2] = wsf[P_BIH + (c*3+1)*kG + g];
    bh1n[t2] = wsf[P_BHH + (c*3+1)*kG + g];
    bi2n[t2] = wsf[P_BIH + (c*3+2)*kG + g];
    bh2n[t2] = wsf[P_BHH + (c*3+2)*kG + g];
  }

  float h0s[8], h1s[8], h2s[8];
#pragma unroll
  for (int i = 0; i < 8; ++i) { h0s[i] = 0.f; h1s[i] = 0.f; h2s[i] = 0.f; }

  unsigned short* outsAll = (unsigned short*)wsf;
  unsigned short* outsC = outsAll + (size_t)(c*kB + b) * (kR*kS*kH);
  const unsigned short* outsP = outsAll + (size_t)(((c > 0 ? c : 1) - 1)*kB + b) * (kR*kS*kH);
  int* prog = (int*)(wsf + PROG_OFF);
  const int* xc = x + (b*3 + c) * kR * kS;
  const float* Tc = wsf + T_OFF + (size_t)c * kV * kG;

  int rr0[4]; float rpw[4];
#pragma unroll
  for (int i = 0; i < 4; ++i) {
    rr0[i] = cb0 + q*4 + i;
    rpw[i] = (float)rr0[i] * (2.0f/64.0f) - 1.0f;
  }

  // ---- prefetch state: T values and producer-outs fragment, one diag ahead ----
  float tv[6][4];
  bfrag poPre;
  auto load_tv = [&](int dd) {
#pragma unroll
    for (int i = 0; i < 4; ++i) {
      int sv = dd - rr0[i];
      int scl = sv < 0 ? 0 : (sv > 63 ? 63 : sv);
      int xiv = xc[rr0[i]*kS + scl];
      const float* tp = Tc + (size_t)xiv*kG;
#pragma unroll
      for (int u = 0; u < 6; ++u) tv[u][i] = tp[u*16 + ln];
    }
  };
  auto load_po = [&](int dd) {
    int sv = dd - (cb0 + m);
    int scl = sv < 0 ? 0 : (sv > 63 ? 63 : sv);
    poPre = *(const bfrag*)&outsP[((size_t)(cb0 + m)*kS + scl)*kH + q*8];
  };
  load_tv(cb0);           // safe pre-loop: T is static
#pragma unroll
  for (int j = 0; j < 8; ++j) poPre[j] = 0;   // first real po load happens in-loop, gated by prog

  __syncthreads();

  constexpr int DELTA = 4;
  constexpr int TT = (kR + kS - 1) + 2*DELTA;   // 135
  for (int t = 0; t < TT; ++t) {
    const int d = t - c*DELTA;

    // phase 1 (tid0): release prev diagonal (stores drained pre-barB last step),
    // then acquire producer progress needed for THIS step's po prefetch (d+1).
    if (tid == 0) {
      if (c < 2 && d >= 1 && d <= 127)
        __hip_atomic_store(&prog[c*16 + b], d, __ATOMIC_RELEASE, __HIP_MEMORY_SCOPE_AGENT);
      if (c > 0 && d >= -1 && d <= 125) {
        const int need = d + 2;
        while (__hip_atomic_load(&prog[(c-1)*16 + b], __ATOMIC_ACQUIRE,
                                 __HIP_MEMORY_SCOPE_AGENT) < need) { }
      }
    }
    lds_barrier();   // barA: progress + ring(d-1) visible WG-wide

    const bool activ = (d >= cb0) && (d <= cb0 + 78);
    if (activ) {
      const int ps = (d - 1) & 1;
      const int cs = d & 1;

      int ssv[4];
      bool act[4];
#pragma unroll
      for (int i = 0; i < 4; ++i) {
        ssv[i] = d - rr0[i];
        act[i] = ((unsigned)ssv[i]) < 64u;
      }
      const int row = cb0 + m;

      bfrag phA, h0A;
      {
        int pr = row - 1;
        int prc = pr < 0 ? 0 : pr;
        phA = *(const bfrag*)&RING[ps][prc][q*8];
        if (pr < 0) {
#pragma unroll
          for (int j = 0; j < 8; ++j) phA[j] = 0;
        }
        h0A = *(const bfrag*)&H0L[row][q*8];
      }
      bfrag poA = poPre;   // prefetched last iteration

      // ---- layer 0: zero-init, MFMA chain, T-add after (R4-verified) ----
      ffrag rz[4], gn[2], hn[2];
#pragma unroll
      for (int u = 0; u < 4; ++u)
#pragma unroll
        for (int i = 0; i < 4; ++i) rz[u][i] = 0.f;
#pragma unroll
      for (int t2 = 0; t2 < 2; ++t2)
#pragma unroll
        for (int i = 0; i < 4; ++i) { gn[t2][i] = 0.f; hn[t2][i] = bh0n[t2]; }

#pragma unroll
      for (int u = 0; u < 4; ++u)
        rz[u] = MFMA16(phA, Wb[0][u], rz[u]);
#pragma unroll
      for (int t2 = 0; t2 < 2; ++t2)
        gn[t2] = MFMA16(phA, Wb[0][4+t2], gn[t2]);
      if (c > 0) {
#pragma unroll
        for (int u = 0; u < 4; ++u)
          rz[u] = MFMA16(poA, Wb[6][u], rz[u]);
#pragma unroll
        for (int t2 = 0; t2 < 2; ++t2)
          gn[t2] = MFMA16(poA, Wb[6][4+t2], gn[t2]);
      }
#pragma unroll
      for (int u = 0; u < 4; ++u)
        rz[u] = MFMA16(h0A, Wb[1][u], rz[u]);
#pragma unroll
      for (int t2 = 0; t2 < 2; ++t2)
        hn[t2] = MFMA16(h0A, Wb[1][4+t2], hn[t2]);

      // consume prefetched T (garbage lanes masked by act)
#pragma unroll
      for (int u = 0; u < 4; ++u)
#pragma unroll
        for (int i = 0; i < 4; ++i) rz[u][i] += tv[u][i] + rpw[i]*rwt[u];
#pragma unroll
      for (int t2 = 0; t2 < 2; ++t2)
#pragma unroll
        for (int i = 0; i < 4; ++i) gn[t2][i] += tv[4+t2][i] + rpw[i]*rwt[4+t2];

      // issue next-step prefetches EARLY so they age across layers 1-2
      if (d + 1 <= cb0 + 78) {
        load_tv(d + 1);
        if (c > 0) load_po(d + 1);
      }

#pragma unroll
      for (int i = 0; i < 4; ++i)
#pragma unroll
        for (int th = 0; th < 2; ++th) {
          float rg = sigm(rz[th][i]);
          float zg = sigm(rz[2+th][i]);
          float ng = tanh_(gn[th][i] + rg*hn[th][i]);
          float h0v = (1.f - zg)*ng + zg*h0s[i*2+th];
          if (act[i]) {
            h0s[i*2+th] = h0v;
            H0L[rr0[i]][th*16 + ln] = f2b(h0v);
          }
        }
      bfrag h0An = *(const bfrag*)&H0L[row][q*8];

      // ---- layer 1 ----
      bfrag h1A = *(const bfrag*)&H1L[row][q*8];
      ffrag rz1[4], gn1[2], hn1[2];
#pragma unroll
      for (int u = 0; u < 4; ++u)
#pragma unroll
        for (int i = 0; i < 4; ++i) rz1[u][i] = bi1z[u];
#pragma unroll
      for (int t2 = 0; t2 < 2; ++t2)
#pragma unroll
        for (int i = 0; i < 4; ++i) { gn1[t2][i] = bi1n[t2]; hn1[t2][i] = bh1n[t2]; }
#pragma unroll
      for (int u = 0; u < 4; ++u) {
        rz1[u] = MFMA16(h0An, Wb[2][u], rz1[u]);
        rz1[u] = MFMA16(h1A,  Wb[3][u], rz1[u]);
      }
#pragma unroll
      for (int t2 = 0; t2 < 2; ++t2) {
        gn1[t2] = MFMA16(h0An, Wb[2][4+t2], gn1[t2]);
        hn1[t2] = MFMA16(h1A,  Wb[3][4+t2], hn1[t2]);
      }
#pragma unroll
      for (int i = 0; i < 4; ++i)
#pragma unroll
        for (int th = 0; th < 2; ++th) {
          float rg = sigm(rz1[th][i]);
          float zg = sigm(rz1[2+th][i]);
          float ng = tanh_(gn1[th][i] + rg*hn1[th][i]);
          float h1v = (1.f - zg)*ng + zg*h1s[i*2+th];
          if (act[i]) {
            h1s[i*2+th] = h1v;
            H1L[rr0[i]][th*16 + ln] = f2b(h1v);
          }
        }
      bfrag h1An = *(const bfrag*)&H1L[row][q*8];

      // ---- layer 2 ----
      bfrag h2A = *(const bfrag*)&RING[ps][row][q*8];
      if (m == d - cb0) {            // s==0 row: no left neighbor
#pragma unroll
        for (int j = 0; j < 8; ++j) h2A[j] = 0;
      }
      ffrag rz2[4], gn2[2], hn2[2];
#pragma unroll
      for (int u = 0; u < 4; ++u)
#pragma unroll
        for (int i = 0; i < 4; ++i) rz2[u][i] = bi2z[u];
#pragma unroll
      for (int t2 = 0; t2 < 2; ++t2)
#pragma unroll
        for (int i = 0; i < 4; ++i) { gn2[t2][i] = bi2n[t2]; hn2[t2][i] = bh2n[t2]; }
#pragma unroll
      for (int u = 0; u < 4; ++u) {
        rz2[u] = MFMA16(h1An, Wb[4][u], rz2[u]);
        rz2[u] = MFMA16(h2A,  Wb[5][u], rz2[u]);
      }
#pragma unroll
      for (int t2 = 0; t2 < 2; ++t2) {
        gn2[t2] = MFMA16(h1An, Wb[4][4+t2], gn2[t2]);
        hn2[t2] = MFMA16(h2A,  Wb[5][4+t2], hn2[t2]);
      }
#pragma unroll
      for (int i = 0; i < 4; ++i)
#pragma unroll
        for (int th = 0; th < 2; ++th) {
          float rg = sigm(rz2[th][i]);
          float zg = sigm(rz2[2+th][i]);
          float ng = tanh_(gn2[th][i] + rg*hn2[th][i]);
          float h2old = (ssv[i] == 0) ? 0.f : h2s[i*2+th];
          float h2v = (1.f - zg)*ng + zg*h2old;
          if (act[i]) {
            h2s[i*2+th] = h2v;
            short hb = f2b(h2v);
            RING[cs][rr0[i]][th*16 + ln] = hb;
            outsC[((size_t)rr0[i]*kS + ssv[i])*kH + th*16 + ln] = (unsigned short)hb;
          }
        }
    } else {
      // prologue iterations: issue prefetches for this wave's first diagonal
      if (d + 1 >= cb0 && d + 1 <= cb0 + 78) {
        load_tv(d + 1);
        if (c > 0) load_po(d + 1);
      }
    }

    // producers: drain own vmem (stores fresh ~400cyc; prefetch loads aged)
    // so next step's tid0 release covers all threads' outs stores.
    if (c < 2) {
      __builtin_amdgcn_sched_barrier(0);
      asm volatile("s_waitcnt vmcnt(0)" ::: "memory");
    }
    lds_barrier();   // barB: ring(d)+H01(d) visible for next diagonal
  }
}

// ---------------- logits epilogue: MFMA GEMM ----------------
// out[pos][v] = hv[pos][:32] . W_c[v][:32] + bias_c[v] (+ per-pos table rows;
// the E-dim weight halves were folded into TG/TBR/TBG by prep).
// Grid = 3ch x 16b x 64r WGs; 4 waves/WG, each wave = one 16-pos x 258-v strip.
// A-frag = bf16 outs fragment straight from workspace (same layout recur wrote).
// Weights use a two-term bf16 split (w = hi + lo, 2 MFMAs) so numerics match
// the old fp32-weight scalar path (error ~2^-17 per weight).
__global__ __launch_bounds__(256, 1)
void logits_kernel(const int* __restrict__ target, const float* __restrict__ wsf,
                   float* __restrict__ out)
{
  const int bx = blockIdx.x;
  const int ch = bx >> 10;          // 1024 WGs per channel
  const int b  = (bx >> 6) & 15;
  const int r  = bx & 63;

  const int tid  = threadIdx.x;
  const int wave = tid >> 6;
  const int lane = tid & 63;
  const int ln   = lane & 15;
  const int q    = lane >> 4;

  const int s0  = wave * 16;
  const int rsb = r * 64 + s0;      // first position of this wave's 16-pos strip

  // A-frag: hv[pos = rsb+ln][k = q*8..q*8+7] as raw bf16 bits
  const unsigned short* outsAll = (const unsigned short*)wsf;
  const unsigned short* hvp = outsAll + (size_t)(ch*kB + b)*(kR*kS*kH)
                                      + (size_t)(rsb + ln)*kH + q*8;
  bfrag hvA = *(const bfrag*)hvp;

  // per-accumulator-row targets (row m = q*4+i)
  int trv[4], tgv[4];
  if (ch >= 1) {
    const int* tgt0 = target + (b*3 + 0)*4096;
#pragma unroll
    for (int i = 0; i < 4; ++i) trv[i] = tgt0[rsb + q*4 + i];
  }
  if (ch == 2) {
    const int* tgt1 = target + (b*3 + 1)*4096;
#pragma unroll
    for (int i = 0; i < 4; ++i) tgv[i] = tgt1[rsb + q*4 + i];
  }

  // channel weight/bias bases (WG-uniform)
  const float* wbase; const float* bbase; int wstride;
  if (ch == 0)      { wbase = wsf + P_REDW;   bbase = wsf + P_REDB;   wstride = kH; }
  else if (ch == 1) { wbase = wsf + P_GREENW; bbase = wsf + P_GREENB; wstride = kH + kE; }
  else              { wbase = wsf + P_BLUEW;  bbase = wsf + P_BLUEB;  wstride = kH + 2*kE; }

  const size_t obase = ((size_t)(b*3 + ch)*4096 + rsb);
  const float* TGt  = wsf + TG_OFF;
  const float* TBRt = wsf + TBR_OFF;
  const float* TBGt = wsf + TBG_OFF;

#pragma unroll
  for (int t = 0; t < 17; ++t) {
    const int v0 = t * 16;
    const int vr = v0 + ln;                    // this lane's vocab column
    const int vv = (vr < kV) ? vr : (kV - 1);  // clamped for reads

    // two-term bf16 weight fragments
    bfrag whi, wlo;
    {
      const float* wrow = wbase + (size_t)vv*wstride + q*8;
#pragma unroll
      for (int j = 0; j < 8; ++j) {
        float wv = wrow[j];
        short hi = f2b(wv);
        whi[j] = hi;
        wlo[j] = f2b(wv - b2f(hi));
      }
    }

    // accumulator init: bias + table rows (per row m = q*4+i)
    float bias = bbase[vv];
    ffrag acc;
#pragma unroll
    for (int i = 0; i < 4; ++i) {
      float a = bias;
      if (ch == 1)      a += TGt[(size_t)trv[i]*kV + vv];
      else if (ch == 2) a += TBRt[(size_t)trv[i]*kV + vv] + TBGt[(size_t)tgv[i]*kV + vv];
      acc[i] = a;
    }

    acc = MFMA16(hvA, wlo, acc);
    acc = MFMA16(hvA, whi, acc);

    if (vr < kV) {
#pragma unroll
      for (int i = 0; i < 4; ++i)
        out[(obase + q*4 + i)*kV + vr] = acc[i];
    }
  }
}

extern "C" void kernel_launch(void* const* d_in, const int* in_sizes, int n_in,
                              void* d_out, int out_size, void* d_ws, size_t ws_size,
                              hipStream_t stream)
{
  const int* x      = (const int*)d_in[0];
  const int* target = (const int*)d_in[1];
  float* wsf = (float*)d_ws;

  norm_kernel<<<16, 256, 0, stream>>>(d_in[2], d_in[3], d_in[4], d_in[5], d_in[6], d_in[7],
                                      d_in[8], d_in[9], d_in[10], d_in[11], d_in[12], d_in[13],
                                      d_in[14], d_in[15], d_in[16], d_in[17], wsf);
  const int prepN = 3*kV*kG + 3*kG*kH + 2*kG*kH + 3*kG + 3*kG + 3*kV*kV;
  prep_kernel<<<(prepN + 255)/256, 256, 0, stream>>>(wsf);
  tfold_kernel<<<(3*kV*kG + 255)/256, 256, 0, stream>>>(wsf);
  recur_all_kernel<<<48, 256, 0, stream>>>(x, wsf);
  logits_kernel<<<3*16*64, 256, 0, stream>>>(target, wsf, (float*)d_out);
}